// Round 3
// baseline (72.396 us; speedup 1.0000x reference)
//
#include <hip/hip_runtime.h>
#include <hip/hip_cooperative_groups.h>
#include <math.h>

namespace cg = cooperative_groups;

#define NN 16384
#define DD 1024
#define HD 512

// ws layout (float units):
// [0]                 : (int)  dynamic_k
// [4..14)             : (int)  neighbor_idx[10]
// [32 .. 32+11*1024)  : float  uv[11][1024]   k=0..9 -> v_k, k=10 -> u (x @ W_att1_top)
// [11296 .. +32*512)  : float  hp[32][512]    cnt-MLP hidden partials
#define WS_DK  0
#define WS_NB  4
#define WS_UV  32
#define WS_HP  11296

__global__ void k_fused(const float* __restrict__ x, const float* __restrict__ emb,
                        const float* __restrict__ sim, const float* __restrict__ W1,
                        const float* __restrict__ ba1, const float* __restrict__ W2,
                        const float* __restrict__ ba2, const float* __restrict__ Wc1,
                        const float* __restrict__ bc1, const float* __restrict__ Wc2,
                        const float* __restrict__ bc2, const int* __restrict__ tidx,
                        float* __restrict__ ws, float* __restrict__ out) {
    cg::grid_group grid = cg::this_grid();
    const int t = threadIdx.x;              // 256
    const int b = blockIdx.x;               // 0..128
    const int lane = t & 63, wave = t >> 6;

    __shared__ float xs[32];
    __shared__ float es[10][32];
    __shared__ int   nb[10];
    __shared__ float wvs[4];
    __shared__ int   wgs[4];
    __shared__ int   winner;
    __shared__ int   toplist[11];
    __shared__ float red[256];
    __shared__ float sc[10];
    __shared__ float wl[10];

    // ================= phase 1 =================
    if (b < 32) {
        // cnt-MLP hidden partials: chunk b covers rows [b*32, b*32+32), all 512 j's
        const int ibase = b * 32;
        if (t < 32) xs[t] = x[ibase + t];
        __syncthreads();
        #pragma unroll
        for (int jj = 0; jj < 2; ++jj) {
            const int j = t + jj * 256;
            float acc = 0.f;
            const float* W = Wc1 + (size_t)ibase * HD + j;
            #pragma unroll 8
            for (int ii = 0; ii < 32; ++ii) acc += xs[ii] * W[(size_t)ii * HD];
            ws[WS_HP + b * HD + j] = acc;
        }
    } else if (b == 32) {
        // zero uv accumulators (consumed by phase-2 atomics)
        for (int i = t; i < 11 * DD; i += 256) ws[WS_UV + i] = 0.f;
    } else if (b == 33) {
        // deterministic top-11 over the target's similarity row
        const int tgt = tidx[0];
        const float4* row4 = (const float4*)(sim + (size_t)tgt * NN);
        float vals[64];
        #pragma unroll
        for (int c = 0; c < 16; ++c) {
            float4 v = row4[c * 256 + t];
            vals[c * 4 + 0] = v.x; vals[c * 4 + 1] = v.y;
            vals[c * 4 + 2] = v.z; vals[c * 4 + 3] = v.w;
        }
        // vals[s=c*4+q] holds row[gi], gi = c*1024 + t*4 + q (monotone in s for fixed t)
        unsigned long long used = 0ull;
        for (int it = 0; it < 11; ++it) {
            float bv = -INFINITY; int bs = 0;
            #pragma unroll
            for (int s = 0; s < 64; ++s) {
                float v = ((used >> s) & 1ull) ? -INFINITY : vals[s];
                if (v > bv) { bv = v; bs = s; }   // strict > keeps earliest s = smallest gi
            }
            int gi = (bs >> 2) * 1024 + t * 4 + (bs & 3);
            for (int off = 32; off > 0; off >>= 1) {
                float ov = __shfl_down(bv, off);
                int   og = __shfl_down(gi, off);
                if (ov > bv || (ov == bv && og < gi)) { bv = ov; gi = og; }
            }
            if (lane == 0) { wvs[wave] = bv; wgs[wave] = gi; }
            __syncthreads();
            if (t == 0) {
                float fv = wvs[0]; int fg = wgs[0];
                for (int w = 1; w < 4; ++w)
                    if (wvs[w] > fv || (wvs[w] == fv && wgs[w] < fg)) { fv = wvs[w]; fg = wgs[w]; }
                toplist[it] = fg;
                winner = fg;
            }
            __syncthreads();
            int w = winner;
            if (((w >> 2) & 255) == t) used |= 1ull << ((w >> 10) * 4 + (w & 3));
        }
        if (t == 0) {
            // stable compaction: drop target_idx if present, else drop the 11th
            int cnt = 0;
            int* nbp = (int*)ws + WS_NB;
            for (int i = 0; i < 11 && cnt < 10; ++i) {
                int v = toplist[i];
                if (v != tgt) { nbp[cnt] = v; out[1034 + cnt] = (float)v; ++cnt; }
            }
        }
    } else if (b < 128) {
        // prefetch this block's phase-2 W1 chunk into its CU/XCD L2
        const int jc = b & 3, ic = b >> 2;
        const int ibase = ic * 32;
        const int j = jc * 256 + t;
        float s = 0.f;
        const float* Wt = W1 + (size_t)ibase * DD + j;
        const float* Wb = W1 + (size_t)(1024 + ibase) * DD + j;
        for (int ii = 0; ii < 32; ++ii) s += Wt[(size_t)ii * DD] + Wb[(size_t)ii * DD];
        if (s == -1e30f) ws[WS_UV] = s;   // unprovably-false: keeps loads live
    }

    grid.sync();

    // ================= phase 2 =================
    if (b < 128) {
        // attention GEMM: uv[k][j] += emb_k[i-chunk] . W1_bot[i-chunk, j]  (k=10: x . W1_top)
        const int jc = b & 3, ic = b >> 2;
        const int ibase = ic * 32;
        const int j = jc * 256 + t;
        if (t < 10) nb[t] = ((const int*)ws)[WS_NB + t];
        if (t < 32) xs[t] = x[ibase + t];
        __syncthreads();
        for (int idx = t; idx < 320; idx += 256) {
            int k = idx >> 5, ii = idx & 31;
            es[k][ii] = emb[(size_t)nb[k] * DD + ibase + ii];
        }
        __syncthreads();
        float acc[11];
        #pragma unroll
        for (int k = 0; k < 11; ++k) acc[k] = 0.f;
        const float* Wt = W1 + (size_t)ibase * DD + j;
        const float* Wb = W1 + (size_t)(1024 + ibase) * DD + j;
        for (int ii = 0; ii < 32; ++ii) {
            float wt = Wt[(size_t)ii * DD];
            float wb = Wb[(size_t)ii * DD];
            acc[10] += xs[ii] * wt;
            #pragma unroll
            for (int k = 0; k < 10; ++k) acc[k] += es[k][ii] * wb;
        }
        #pragma unroll
        for (int k = 0; k < 11; ++k) atomicAdd(&ws[WS_UV + k * DD + j], acc[k]);
    } else {
        // b == 128: cnt-MLP finish -> dynamic_k (deterministic fixed-order sums)
        float acc = 0.f;
        #pragma unroll
        for (int jj = 0; jj < 2; ++jj) {
            int j = t + jj * 256;
            float s = 0.f;
            #pragma unroll 8
            for (int c = 0; c < 32; ++c) s += ws[WS_HP + c * HD + j];
            float h = fmaxf(s + bc1[j], 0.f);
            acc += h * Wc2[j];
        }
        red[t] = acc;
        __syncthreads();
        for (int off = 128; off > 0; off >>= 1) {
            if (t < off) red[t] += red[t + off];
            __syncthreads();
        }
        if (t == 0) {
            float z = red[0] + bc2[0];
            float frac = 1.f / (1.f + expf(-z));
            int dk = (int)floorf(frac * 10.f);
            ((int*)ws)[WS_DK] = dk < 1 ? 1 : (dk > 10 ? 10 : dk);
        }
    }

    grid.sync();

    // ================= phase 3 =================
    if (b == 0) {
        if (t < 10) nb[t] = ((const int*)ws)[WS_NB + t];
        __syncthreads();
        // scores: one wave per k (waves 0..3 cover k = wave, wave+4, wave+8)
        for (int k = wave; k < 10; k += 4) {
            float acc = 0.f;
            #pragma unroll
            for (int m = 0; m < 16; ++m) {
                int j = lane + m * 64;
                float h = ws[WS_UV + 10 * DD + j] + ws[WS_UV + k * DD + j] + ba1[j];
                acc += fmaxf(h, 0.f) * W2[j];
            }
            #pragma unroll
            for (int off = 32; off > 0; off >>= 1) acc += __shfl_down(acc, off);
            if (lane == 0) sc[k] = acc + ba2[0];
        }
        __syncthreads();
        if (t == 0) {
            int dk = ((const int*)ws)[WS_DK];
            float v[10];
            float m = -INFINITY;
            for (int k = 0; k < 10; ++k) {
                v[k] = (k < dk) ? sc[k] : -INFINITY;
                if (v[k] > m) m = v[k];
            }
            float sum = 0.f;
            for (int k = 0; k < 10; ++k) { v[k] = expf(v[k] - m); sum += v[k]; }
            for (int k = 0; k < 10; ++k) wl[k] = v[k] / sum;
        }
        __syncthreads();
        #pragma unroll
        for (int jj = 0; jj < 4; ++jj) {
            int j = t + jj * 256;
            float a = 0.f;
            #pragma unroll
            for (int k = 0; k < 10; ++k) a += wl[k] * emb[(size_t)nb[k] * DD + j];
            out[j] = a;
        }
        if (t < 10) { out[1024 + t] = wl[t]; out[1044 + t] = wl[t]; }
    }
}

extern "C" void kernel_launch(void* const* d_in, const int* in_sizes, int n_in,
                              void* d_out, int out_size, void* d_ws, size_t ws_size,
                              hipStream_t stream) {
    const float* x    = (const float*)d_in[0];   // target_embedding [1024]
    const float* emb  = (const float*)d_in[1];   // all_embeddings [16384,1024]
    const float* sim  = (const float*)d_in[2];   // similarity_matrix [16384,16384]
    const float* W1   = (const float*)d_in[3];   // W_att1 [2048,1024]
    const float* ba1  = (const float*)d_in[4];   // b_att1 [1024]
    const float* W2   = (const float*)d_in[5];   // W_att2 [1024]
    const float* ba2  = (const float*)d_in[6];   // b_att2 [1]
    const float* Wc1  = (const float*)d_in[7];   // W_cnt1 [1024,512]
    const float* bc1  = (const float*)d_in[8];   // b_cnt1 [512]
    const float* Wc2  = (const float*)d_in[9];   // W_cnt2 [512]
    const float* bc2  = (const float*)d_in[10];  // b_cnt2 [1]
    const int*   tidx = (const int*)d_in[11];    // target_idx [1]
    float* out = (float*)d_out;
    float* ws  = (float*)d_ws;

    void* args[] = {(void*)&x, (void*)&emb, (void*)&sim, (void*)&W1, (void*)&ba1,
                    (void*)&W2, (void*)&ba2, (void*)&Wc1, (void*)&bc1, (void*)&Wc2,
                    (void*)&bc2, (void*)&tidx, (void*)&ws, (void*)&out};
    hipLaunchCooperativeKernel((void*)k_fused, dim3(129), dim3(256), args, 0, stream);
}

// Round 4
// 44.767 us; speedup vs baseline: 1.6171x; 1.6171x over previous
//
#include <hip/hip_runtime.h>
#include <math.h>

#define NN 16384
#define DD 1024
#define HD 512

// ws layout (float units):
// [0]                 : (int)  dynamic_k
// [2]                 : (int)  arrival counter for K2 last-block election
// [4..14)             : (int)  neighbor_idx[10]
// [32 .. 32+11*1024)  : float  uv[11][1024]   k=0..9 -> v_k, k=10 -> u (x @ W_att1_top)
// [11296 .. +32*512)  : float  hp[32][512]    cnt-MLP hidden partials
#define WS_DK  0
#define WS_CTR 2
#define WS_NB  4
#define WS_UV  32
#define WS_HP  11296

// ================= K1: blocks 0..31 cnt-MLP partials; 32 zero uv+ctr; 33 top-11 =================
__global__ void __launch_bounds__(256) k1(const float* __restrict__ x,
                                          const float* __restrict__ Wc1,
                                          const float* __restrict__ sim,
                                          const int* __restrict__ tidx,
                                          float* __restrict__ ws,
                                          float* __restrict__ out) {
    const int t = threadIdx.x;              // 256
    const int b = blockIdx.x;               // 0..33
    const int lane = t & 63, wave = t >> 6;

    if (b < 32) {
        // cnt-MLP hidden partials: chunk b covers rows [b*32, b*32+32), all 512 j's
        __shared__ float xs[32];
        const int ibase = b * 32;
        if (t < 32) xs[t] = x[ibase + t];
        __syncthreads();
        #pragma unroll
        for (int jj = 0; jj < 2; ++jj) {
            const int j = t + jj * 256;
            float acc = 0.f;
            const float* W = Wc1 + (size_t)ibase * HD + j;
            #pragma unroll 8
            for (int ii = 0; ii < 32; ++ii) acc += xs[ii] * W[(size_t)ii * HD];
            ws[WS_HP + b * HD + j] = acc;
        }
        return;
    }
    if (b == 32) {
        // zero uv accumulators + arrival counter (consumed by K2)
        for (int i = t; i < 11 * DD; i += 256) ws[WS_UV + i] = 0.f;
        if (t == 0) ((int*)ws)[WS_CTR] = 0;
        return;
    }

    // ---- b == 33: deterministic top-11 over the target's similarity row ----
    const int tgt = tidx[0];
    const float4* row4 = (const float4*)(sim + (size_t)tgt * NN);
    float vals[64];
    #pragma unroll
    for (int c = 0; c < 16; ++c) {
        float4 v = row4[c * 256 + t];
        vals[c * 4 + 0] = v.x; vals[c * 4 + 1] = v.y;
        vals[c * 4 + 2] = v.z; vals[c * 4 + 3] = v.w;
    }
    // vals[s=c*4+q] holds row[gi], gi = c*1024 + t*4 + q (monotone in s for fixed t)
    // cached per-thread local best; strict > keeps earliest s = smallest gi
    float bv = -INFINITY; int bs = 0;
    #pragma unroll
    for (int s = 0; s < 64; ++s) if (vals[s] > bv) { bv = vals[s]; bs = s; }

    __shared__ float wvs[4];
    __shared__ int   wgs[4];
    __shared__ int   winner;
    __shared__ int   toplist[11];

    for (int it = 0; it < 11; ++it) {
        float cv = bv;
        int   cg = (bs >> 2) * 1024 + t * 4 + (bs & 3);
        // wave reduce: larger val, tie -> smaller global idx
        for (int off = 32; off > 0; off >>= 1) {
            float ov = __shfl_down(cv, off);
            int   og = __shfl_down(cg, off);
            if (ov > cv || (ov == cv && og < cg)) { cv = ov; cg = og; }
        }
        if (lane == 0) { wvs[wave] = cv; wgs[wave] = cg; }
        __syncthreads();
        if (t == 0) {
            float fv = wvs[0]; int fg = wgs[0];
            for (int w = 1; w < 4; ++w)
                if (wvs[w] > fv || (wvs[w] == fv && wgs[w] < fg)) { fv = wvs[w]; fg = wgs[w]; }
            toplist[it] = fg;
            winner = fg;
        }
        __syncthreads();
        const int w = winner;
        if (((w >> 2) & 255) == t) {
            // this thread owned the winner: mask that slot, rescan its 64 values
            vals[((w >> 10) << 2) | (w & 3)] = -INFINITY;
            bv = -INFINITY; bs = 0;
            #pragma unroll
            for (int s = 0; s < 64; ++s) if (vals[s] > bv) { bv = vals[s]; bs = s; }
        }
    }
    if (t == 0) {
        // stable compaction: drop target_idx if present, else drop the 11th
        int cnt = 0;
        int* nbp = (int*)ws + WS_NB;
        for (int i = 0; i < 11 && cnt < 10; ++i) {
            int v = toplist[i];
            if (v != tgt) { nbp[cnt] = v; out[1034 + cnt] = (float)v; ++cnt; }
        }
    }
}

// ====== K2: blocks 0..127 attention GEMM; block 128 cnt-final; last-done block runs phase C ======
__global__ void __launch_bounds__(256) k2(const float* __restrict__ x,
                                          const float* __restrict__ emb,
                                          const float* __restrict__ W1,
                                          const float* __restrict__ ba1,
                                          const float* __restrict__ W2,
                                          const float* __restrict__ ba2,
                                          const float* __restrict__ bc1,
                                          const float* __restrict__ Wc2,
                                          const float* __restrict__ bc2,
                                          float* __restrict__ ws,
                                          float* __restrict__ out) {
    const int t = threadIdx.x;              // 256
    const int b = blockIdx.x;               // 0..128
    const int lane = t & 63, wave = t >> 6;

    __shared__ float xs[32];
    __shared__ float es[10][32];
    __shared__ int   nb[10];
    __shared__ float red[256];
    __shared__ float sc[10];
    __shared__ float wl[10];
    __shared__ int   lastFlag;

    if (b < 128) {
        // attention GEMM: uv[k][j] += emb_k[i-chunk] . W1_bot[i-chunk, j]  (k=10: x . W1_top)
        const int jc = b & 3, ic = b >> 2;
        const int ibase = ic * 32;
        const int j = jc * 256 + t;
        if (t < 10) nb[t] = ((const int*)ws)[WS_NB + t];
        if (t < 32) xs[t] = x[ibase + t];
        __syncthreads();
        for (int idx = t; idx < 320; idx += 256) {
            int k = idx >> 5, ii = idx & 31;
            es[k][ii] = emb[(size_t)nb[k] * DD + ibase + ii];
        }
        __syncthreads();
        float acc[11];
        #pragma unroll
        for (int k = 0; k < 11; ++k) acc[k] = 0.f;
        const float* Wt = W1 + (size_t)ibase * DD + j;
        const float* Wb = W1 + (size_t)(1024 + ibase) * DD + j;
        for (int ii = 0; ii < 32; ++ii) {
            float wt = Wt[(size_t)ii * DD];
            float wb = Wb[(size_t)ii * DD];
            acc[10] += xs[ii] * wt;
            #pragma unroll
            for (int k = 0; k < 10; ++k) acc[k] += es[k][ii] * wb;
        }
        #pragma unroll
        for (int k = 0; k < 11; ++k) atomicAdd(&ws[WS_UV + k * DD + j], acc[k]);
    } else {
        // b == 128: cnt-MLP finish -> dynamic_k (deterministic fixed-order sums)
        float acc = 0.f;
        #pragma unroll
        for (int jj = 0; jj < 2; ++jj) {
            int j = t + jj * 256;
            float s = 0.f;
            #pragma unroll 8
            for (int c = 0; c < 32; ++c) s += ws[WS_HP + c * HD + j];
            float h = fmaxf(s + bc1[j], 0.f);
            acc += h * Wc2[j];
        }
        red[t] = acc;
        __syncthreads();
        for (int off = 128; off > 0; off >>= 1) {
            if (t < off) red[t] += red[t + off];
            __syncthreads();
        }
        if (t == 0) {
            float z = red[0] + bc2[0];
            float frac = 1.f / (1.f + expf(-z));
            int dk = (int)floorf(frac * 10.f);
            ((int*)ws)[WS_DK] = dk < 1 ? 1 : (dk > 10 ? 10 : dk);
        }
    }

    // ---- last-block-done election (129 arrivals) ----
    __syncthreads();                 // all threads' atomics/stores issued & drained (vmcnt at barrier)
    __threadfence();                 // release: make them device-visible
    if (t == 0) lastFlag = (atomicAdd((int*)ws + WS_CTR, 1) == 128);
    __syncthreads();
    if (!lastFlag) return;
    __threadfence();                 // acquire: see all blocks' uv/dk writes

    // ================= phase C: scores + softmax + aggregate + outputs =================
    if (t < 10) nb[t] = ((const int*)ws)[WS_NB + t];
    __syncthreads();
    for (int k = wave; k < 10; k += 4) {
        float acc = 0.f;
        #pragma unroll
        for (int m = 0; m < 16; ++m) {
            int j = lane + m * 64;
            float h = ws[WS_UV + 10 * DD + j] + ws[WS_UV + k * DD + j] + ba1[j];
            acc += fmaxf(h, 0.f) * W2[j];
        }
        #pragma unroll
        for (int off = 32; off > 0; off >>= 1) acc += __shfl_down(acc, off);
        if (lane == 0) sc[k] = acc + ba2[0];
    }
    __syncthreads();
    if (t == 0) {
        int dk = ((const int*)ws)[WS_DK];
        float v[10];
        float m = -INFINITY;
        for (int k = 0; k < 10; ++k) {
            v[k] = (k < dk) ? sc[k] : -INFINITY;
            if (v[k] > m) m = v[k];
        }
        float sum = 0.f;
        for (int k = 0; k < 10; ++k) { v[k] = expf(v[k] - m); sum += v[k]; }
        for (int k = 0; k < 10; ++k) wl[k] = v[k] / sum;
    }
    __syncthreads();
    #pragma unroll
    for (int jj = 0; jj < 4; ++jj) {
        int j = t + jj * 256;
        float a = 0.f;
        #pragma unroll
        for (int k = 0; k < 10; ++k) a += wl[k] * emb[(size_t)nb[k] * DD + j];
        out[j] = a;
    }
    if (t < 10) { out[1024 + t] = wl[t]; out[1044 + t] = wl[t]; }
}

extern "C" void kernel_launch(void* const* d_in, const int* in_sizes, int n_in,
                              void* d_out, int out_size, void* d_ws, size_t ws_size,
                              hipStream_t stream) {
    const float* x    = (const float*)d_in[0];   // target_embedding [1024]
    const float* emb  = (const float*)d_in[1];   // all_embeddings [16384,1024]
    const float* sim  = (const float*)d_in[2];   // similarity_matrix [16384,16384]
    const float* W1   = (const float*)d_in[3];   // W_att1 [2048,1024]
    const float* ba1  = (const float*)d_in[4];   // b_att1 [1024]
    const float* W2   = (const float*)d_in[5];   // W_att2 [1024]
    const float* ba2  = (const float*)d_in[6];   // b_att2 [1]
    const float* Wc1  = (const float*)d_in[7];   // W_cnt1 [1024,512]
    const float* bc1  = (const float*)d_in[8];   // b_cnt1 [512]
    const float* Wc2  = (const float*)d_in[9];   // W_cnt2 [512]
    const float* bc2  = (const float*)d_in[10];  // b_cnt2 [1]
    const int*   tidx = (const int*)d_in[11];    // target_idx [1]
    float* out = (float*)d_out;
    float* ws  = (float*)d_ws;

    hipLaunchKernelGGL(k1, dim3(34),  dim3(256), 0, stream, x, Wc1, sim, tidx, ws, out);
    hipLaunchKernelGGL(k2, dim3(129), dim3(256), 0, stream,
                       x, emb, W1, ba1, W2, ba2, bc1, Wc2, bc2, ws, out);
}